// Round 17
// baseline (559.293 us; speedup 1.0000x reference)
//
#include <hip/hip_runtime.h>
#include <math.h>

#define BB 32
#define TT 128
#define EE 128
#define HD 128
#define G4 512   // 4*H
#define NV 32000

typedef _Float16 f16x2  __attribute__((ext_vector_type(2)));
typedef _Float16 f16x4v __attribute__((ext_vector_type(4)));
typedef _Float16 f16x8  __attribute__((ext_vector_type(8)));
typedef float    f32x4  __attribute__((ext_vector_type(4)));

// ---------------- Kernel A: embed + W0 -> Z0x ----------------
__global__ __launch_bounds__(256) void k_embed(
    const int* __restrict__ inputs, const float* __restrict__ emb,
    const float* __restrict__ W0, const float* __restrict__ b0,
    float* __restrict__ Z0x)
{
    __shared__ float xs[8][EE];
    const int r0 = blockIdx.x * 8;
    const int tid = threadIdx.x;
    for (int i = tid; i < 8 * EE; i += 256) {
        int r = i >> 7, e = i & 127;
        int tok = inputs[r0 + r];
        xs[r][e] = emb[tok * EE + e];
    }
    __syncthreads();
    const int c2 = tid * 2;
    float2 bb2 = *(const float2*)&b0[c2];
    float acc[8][2];
    #pragma unroll
    for (int r = 0; r < 8; ++r) { acc[r][0] = bb2.x; acc[r][1] = bb2.y; }
    for (int e = 0; e < EE; ++e) {
        float2 w = *(const float2*)&W0[e * G4 + c2];
        #pragma unroll
        for (int r = 0; r < 8; ++r) {
            float x = xs[r][e];
            acc[r][0] = fmaf(x, w.x, acc[r][0]);
            acc[r][1] = fmaf(x, w.y, acc[r][1]);
        }
    }
    #pragma unroll
    for (int r = 0; r < 8; ++r) {
        float2 o2; o2.x = acc[r][0]; o2.y = acc[r][1];
        *(float2*)&Z0x[(size_t)(r0 + r) * G4 + c2] = o2;
    }
}

// ---------------- Kernel B: LSTM 8-wave (blocks 0-3) + fused wsplit (blocks 4..1003) ----------------
// 512 thr / 8 waves, 2 waves/SIMD (latency hiding). Wave w owns 64 gate
// columns (4 ntiles): U0 16 frags = 64 VGPR (fits the 128-V cap at 512 thr),
// W1+U1 32 frags = 128 AGPR. Same R13-verified fragments/zbuf/barriers.
__device__ __forceinline__ float sigf(float x) {
    return __builtin_amdgcn_rcpf(1.f + __builtin_amdgcn_exp2f(x * -1.44269504088896f));
}
__device__ __forceinline__ float tanh_f(float x) {
    return 1.f - 2.f * __builtin_amdgcn_rcpf(1.f + __builtin_amdgcn_exp2f(x * 2.88539008177793f));
}
__device__ __forceinline__ f16x8 ldfrag(const float* __restrict__ M, int col, int k0) {
    f16x8 v;
    #pragma unroll
    for (int j = 0; j < 8; ++j) v[j] = (_Float16)M[(size_t)(k0 + j) * G4 + col];
    return v;
}

#define REP4(X) X(0) X(1) X(2) X(3)
#define MFMA(acc, a, b) acc = __builtin_amdgcn_mfma_f32_16x16x32_f16(a, b, acc, 0, 0, 0)

#define DECLF(n) f16x8 u0_##n##_0, u0_##n##_1, u0_##n##_2, u0_##n##_3, \
                       w1_##n##_0, w1_##n##_1, w1_##n##_2, w1_##n##_3, \
                       u1_##n##_0, u1_##n##_1, u1_##n##_2, u1_##n##_3;

#define LOADF(n) { const int cn = wu0 + (n) * 16 + lo16; \
    u0_##n##_0 = ldfrag(U0, cn, khi);      u0_##n##_1 = ldfrag(U0, cn, 32 + khi); \
    u0_##n##_2 = ldfrag(U0, cn, 64 + khi); u0_##n##_3 = ldfrag(U0, cn, 96 + khi); \
    w1_##n##_0 = ldfrag(W1, cn, khi);      w1_##n##_1 = ldfrag(W1, cn, 32 + khi); \
    w1_##n##_2 = ldfrag(W1, cn, 64 + khi); w1_##n##_3 = ldfrag(W1, cn, 96 + khi); \
    asm("" : "+a"(w1_##n##_0), "+a"(w1_##n##_1), "+a"(w1_##n##_2), "+a"(w1_##n##_3)); \
    u1_##n##_0 = ldfrag(U1, cn, khi);      u1_##n##_1 = ldfrag(U1, cn, 32 + khi); \
    u1_##n##_2 = ldfrag(U1, cn, 64 + khi); u1_##n##_3 = ldfrag(U1, cn, 96 + khi); \
    asm("" : "+a"(u1_##n##_0), "+a"(u1_##n##_1), "+a"(u1_##n##_2), "+a"(u1_##n##_3)); }

#define PA(n) { f32x4 acc = {0.f, 0.f, 0.f, 0.f}; \
    MFMA(acc, ha0, u0_##n##_0); MFMA(acc, ha1, u0_##n##_1); \
    MFMA(acc, ha2, u0_##n##_2); MFMA(acc, ha3, u0_##n##_3); \
    if (lane < 32) { const int cw = wu0 + (n) * 16 + lo16; const int br = (lane >> 4) * 4; \
        zbuf[br + 0][cw] = acc[0]; zbuf[br + 1][cw] = acc[1]; \
        zbuf[br + 2][cw] = acc[2]; zbuf[br + 3][cw] = acc[3]; } }

#define PC(n) { f32x4 acc = {0.f, 0.f, 0.f, 0.f}; \
    MFMA(acc, ha0, w1_##n##_0); MFMA(acc, ha1, w1_##n##_1); \
    MFMA(acc, ha2, w1_##n##_2); MFMA(acc, ha3, w1_##n##_3); \
    MFMA(acc, hb0, u1_##n##_0); MFMA(acc, hb1, u1_##n##_1); \
    MFMA(acc, hb2, u1_##n##_2); MFMA(acc, hb3, u1_##n##_3); \
    if (lane < 32) { const int cw = wu0 + (n) * 16 + lo16; const int br = (lane >> 4) * 4; \
        zbuf[br + 0][cw] = acc[0]; zbuf[br + 1][cw] = acc[1]; \
        zbuf[br + 2][cw] = acc[2]; zbuf[br + 3][cw] = acc[3]; } }

// 2 gate-cells per thread (components x,y of float2)
#define GT0C(C, ZI, ZF, ZC, ZO) { \
    float ig = sigf(ZI), fg = sigf(ZF), og = sigf(ZO), gg = tanh_f(ZC); \
    float cn = fg * c0v.C + ig * gg; c0v.C = cn; hv.C = og * tanh_f(cn); }

#define GT1C(C, ZI, ZF, ZC, ZO) { \
    float ig = sigf(ZI), fg = sigf(ZF), og = sigf(ZO), gg = tanh_f(ZC); \
    float cn = fg * c1v.C + ig * gg; c1v.C = cn; hv.C = og * tanh_f(cn); }

__global__ __launch_bounds__(512, 2) void k_lstm_w8(
    const float* __restrict__ Z0x,
    const float* __restrict__ U0, const float* __restrict__ W1,
    const float* __restrict__ U1, const float* __restrict__ b1,
    float* __restrict__ y,
    const float* __restrict__ Wd, _Float16* __restrict__ Whi, _Float16* __restrict__ Wlo)
{
    const int tid  = threadIdx.x;

    if (blockIdx.x >= 4) {
        // ---- fused Wd hi/lo split (independent work on idle CUs) ----
        if (Whi == nullptr) return;
        const int g = (blockIdx.x - 4) * 512 + tid;
        const int chunk = g >> 6;           // 0..7999
        const int ln = g & 63;
        const int ntile = chunk >> 2;
        const int kstep = chunk & 3;
        const int n = ntile * 16 + (ln & 15);
        const int kb = kstep * 32 + (ln >> 4) * 8;
        _Float16 hi[8], lo[8];
        #pragma unroll
        for (int j = 0; j < 8; ++j) {
            float v = Wd[(size_t)(kb + j) * NV + n];
            hi[j] = (_Float16)v;
            lo[j] = (_Float16)(v - (float)hi[j]);
        }
        *(float4*)&Whi[(size_t)chunk * 512 + ln * 8] = *(const float4*)hi;
        *(float4*)&Wlo[(size_t)chunk * 512 + ln * 8] = *(const float4*)lo;
        return;
    }

    const int lane = tid & 63;
    const int wu0  = (tid >> 6) * 64;      // wave's column base (8 waves x 64)
    const int lo16 = lane & 15;
    const int khi  = (lane >> 4) * 8;
    const int B0   = blockIdx.x * 8;       // batch base

    __shared__ float     zbuf[8][516];     // z scores, +4 pad
    __shared__ _Float16  h0p[16][136];     // h0, rows 8-15 stay zero, +8 pad
    __shared__ _Float16  h1p[16][136];

    REP4(DECLF)
    REP4(LOADF)

    // gate-thread mapping: bq = batch, 2 h-units per thread
    const int bq  = tid >> 6;              // 0..7
    const int h0i = (tid & 63) * 2;        // 0..126
    const float* zx_base = Z0x + ((size_t)(B0 + bq) * TT) * G4;
    float*       y_base  = y   + ((size_t)(B0 + bq) * TT) * HD + h0i;

    const float2 b1_i = *(const float2*)&b1[0 * 128 + h0i];
    const float2 b1_f = *(const float2*)&b1[1 * 128 + h0i];
    const float2 b1_c = *(const float2*)&b1[2 * 128 + h0i];
    const float2 b1_o = *(const float2*)&b1[3 * 128 + h0i];

    for (int i = tid; i < 16 * 136; i += 512) {
        ((_Float16*)h0p)[i] = (_Float16)0.f;
        ((_Float16*)h1p)[i] = (_Float16)0.f;
    }
    float2 c0v = {0.f, 0.f};
    float2 c1v = {0.f, 0.f};
    __syncthreads();

    for (int t = 0; t < TT; ++t) {
        // prefetch Z0x gate rows (consumed in gates-0, hidden under MFMA)
        const float* zx = zx_base + (size_t)t * G4;
        const float2 x_i = *(const float2*)&zx[0 * 128 + h0i];
        const float2 x_f = *(const float2*)&zx[1 * 128 + h0i];
        const float2 x_c = *(const float2*)&zx[2 * 128 + h0i];
        const float2 x_o = *(const float2*)&zx[3 * 128 + h0i];

        // ---- phase A: zbuf = U0^T h0_{t-1} ----
        {
            f16x8 ha0 = *(const f16x8*)&h0p[lo16][khi];
            f16x8 ha1 = *(const f16x8*)&h0p[lo16][32 + khi];
            f16x8 ha2 = *(const f16x8*)&h0p[lo16][64 + khi];
            f16x8 ha3 = *(const f16x8*)&h0p[lo16][96 + khi];
            REP4(PA)
        }
        __syncthreads();

        // ---- phase B: layer-0 gates -> h0_t ----
        {
            const float2 zi2 = *(const float2*)&zbuf[bq][0 * 128 + h0i];
            const float2 zf2 = *(const float2*)&zbuf[bq][1 * 128 + h0i];
            const float2 zc2 = *(const float2*)&zbuf[bq][2 * 128 + h0i];
            const float2 zo2 = *(const float2*)&zbuf[bq][3 * 128 + h0i];
            float2 hv;
            GT0C(x, zi2.x + x_i.x, zf2.x + x_f.x, zc2.x + x_c.x, zo2.x + x_o.x)
            GT0C(y, zi2.y + x_i.y, zf2.y + x_f.y, zc2.y + x_c.y, zo2.y + x_o.y)
            f16x2 hp; hp[0] = (_Float16)hv.x; hp[1] = (_Float16)hv.y;
            *(f16x2*)&h0p[bq][h0i] = hp;
        }
        __syncthreads();

        // ---- phase C: zbuf = W1^T h0_t + U1^T h1_{t-1} ----
        {
            f16x8 ha0 = *(const f16x8*)&h0p[lo16][khi];
            f16x8 ha1 = *(const f16x8*)&h0p[lo16][32 + khi];
            f16x8 ha2 = *(const f16x8*)&h0p[lo16][64 + khi];
            f16x8 ha3 = *(const f16x8*)&h0p[lo16][96 + khi];
            f16x8 hb0 = *(const f16x8*)&h1p[lo16][khi];
            f16x8 hb1 = *(const f16x8*)&h1p[lo16][32 + khi];
            f16x8 hb2 = *(const f16x8*)&h1p[lo16][64 + khi];
            f16x8 hb3 = *(const f16x8*)&h1p[lo16][96 + khi];
            REP4(PC)
        }
        __syncthreads();

        // ---- phase D: layer-1 gates -> h1_t, y ----
        {
            const float2 zi2 = *(const float2*)&zbuf[bq][0 * 128 + h0i];
            const float2 zf2 = *(const float2*)&zbuf[bq][1 * 128 + h0i];
            const float2 zc2 = *(const float2*)&zbuf[bq][2 * 128 + h0i];
            const float2 zo2 = *(const float2*)&zbuf[bq][3 * 128 + h0i];
            float2 hv;
            GT1C(x, zi2.x + b1_i.x, zf2.x + b1_f.x, zc2.x + b1_c.x, zo2.x + b1_o.x)
            GT1C(y, zi2.y + b1_i.y, zf2.y + b1_f.y, zc2.y + b1_c.y, zo2.y + b1_o.y)
            f16x2 hp; hp[0] = (_Float16)hv.x; hp[1] = (_Float16)hv.y;
            *(f16x2*)&h1p[bq][h0i] = hp;
            *(float2*)(y_base + (size_t)t * HD) = hv;
        }
        __syncthreads();
    }
}

// ---------------- Prep: split y into f16 hi/lo, MFMA-fragment-packed ----------------
__global__ __launch_bounds__(256) void k_ysplit(
    const float* __restrict__ y, _Float16* __restrict__ yhi, _Float16* __restrict__ ylo)
{
    const int g = blockIdx.x * 256 + threadIdx.x;
    const int chunk = g >> 6;           // 0..1023
    const int lane = g & 63;
    const int mtile = chunk >> 2;
    const int kstep = chunk & 3;
    const int row = mtile * 16 + (lane & 15);
    const int kb = kstep * 32 + (lane >> 4) * 8;
    _Float16 hi[8], lo[8];
    #pragma unroll
    for (int j = 0; j < 8; ++j) {
        float v = y[(size_t)row * HD + kb + j];
        hi[j] = (_Float16)v;
        lo[j] = (_Float16)(v - (float)hi[j]);
    }
    *(float4*)&yhi[(size_t)chunk * 512 + lane * 8] = *(const float4*)hi;
    *(float4*)&ylo[(size_t)chunk * 512 + lane * 8] = *(const float4*)lo;
}

// ---------------- Kernel C (MFMA, B-resident): out = y @ Wd + bd ----------------
__global__ __launch_bounds__(256) void k_dense_mfma2(
    const _Float16* __restrict__ yhi, const _Float16* __restrict__ ylo,
    const _Float16* __restrict__ Whi, const _Float16* __restrict__ Wlo,
    const float* __restrict__ bd, float* __restrict__ out)
{
    const int tid  = threadIdx.x;
    const int w    = tid >> 6;
    const int lane = tid & 63;
    const int nt0  = blockIdx.y * 16 + w * 4;    // wave's 4 ntiles
    const int mt0  = blockIdx.x * 32;            // 32 mtiles per block

    f16x8 Bh[4][4], Bl[4][4];
    #pragma unroll
    for (int n = 0; n < 4; ++n) {
        const size_t cb = (size_t)(nt0 + n) * 4 * 512 + lane * 8;
        #pragma unroll
        for (int k = 0; k < 4; ++k) {
            Bh[n][k] = *(const f16x8*)&Whi[cb + k * 512];
            Bl[n][k] = *(const f16x8*)&Wlo[cb + k * 512];
        }
    }
    float bias[4];
    #pragma unroll
    for (int n = 0; n < 4; ++n) bias[n] = bd[(nt0 + n) * 16 + (lane & 15)];

    const int r0 = (lane >> 4) * 4;              // C/D row group (m89 mapping)

    for (int mt = 0; mt < 32; ++mt) {
        const int mtile = mt0 + mt;
        const size_t ab = (size_t)mtile * 4 * 512 + lane * 8;

        f32x4 acc0[4] = {{0,0,0,0},{0,0,0,0},{0,0,0,0},{0,0,0,0}};
        f32x4 acc1[4] = {{0,0,0,0},{0,0,0,0},{0,0,0,0},{0,0,0,0}};

        {   // A-hi pass: acc0 += Ah*Bh ; acc1 += Ah*Bl
            f16x8 A0 = *(const f16x8*)&yhi[ab];
            f16x8 A1 = *(const f16x8*)&yhi[ab + 512];
            f16x8 A2 = *(const f16x8*)&yhi[ab + 1024];
            f16x8 A3 = *(const f16x8*)&yhi[ab + 1536];
            #pragma unroll
            for (int n = 0; n < 4; ++n) {
                acc0[n] = __builtin_amdgcn_mfma_f32_16x16x32_f16(A0, Bh[n][0], acc0[n], 0, 0, 0);
                acc0[n] = __builtin_amdgcn_mfma_f32_16x16x32_f16(A1, Bh[n][1], acc0[n], 0, 0, 0);
                acc0[n] = __builtin_amdgcn_mfma_f32_16x16x32_f16(A2, Bh[n][2], acc0[n], 0, 0, 0);
                acc0[n] = __builtin_amdgcn_mfma_f32_16x16x32_f16(A3, Bh[n][3], acc0[n], 0, 0, 0);
                acc1[n] = __builtin_amdgcn_mfma_f32_16x16x32_f16(A0, Bl[n][0], acc1[n], 0, 0, 0);
                acc1[n] = __builtin_amdgcn_mfma_f32_16x16x32_f16(A1, Bl[n][1], acc1[n], 0, 0, 0);
                acc1[n] = __builtin_amdgcn_mfma_f32_16x16x32_f16(A2, Bl[n][2], acc1[n], 0, 0, 0);
                acc1[n] = __builtin_amdgcn_mfma_f32_16x16x32_f16(A3, Bl[n][3], acc1[n], 0, 0, 0);
            }
        }
        {   // A-lo pass: acc1 += Al*Bh
            f16x8 A0 = *(const f16x8*)&ylo[ab];
            f16x8 A1 = *(const f16x8*)&ylo[ab + 512];
            f16x8 A2 = *(const f16x8*)&ylo[ab + 1024];
            f16x8 A3 = *(const f16x8*)&ylo[ab + 1536];
            #pragma unroll
            for (int n = 0; n < 4; ++n) {
                acc1[n] = __builtin_amdgcn_mfma_f32_16x16x32_f16(A0, Bh[n][0], acc1[n], 0, 0, 0);
                acc1[n] = __builtin_amdgcn_mfma_f32_16x16x32_f16(A1, Bh[n][1], acc1[n], 0, 0, 0);
                acc1[n] = __builtin_amdgcn_mfma_f32_16x16x32_f16(A2, Bh[n][2], acc1[n], 0, 0, 0);
                acc1[n] = __builtin_amdgcn_mfma_f32_16x16x32_f16(A3, Bh[n][3], acc1[n], 0, 0, 0);
            }
        }
        const int m0 = mtile * 16;
        #pragma unroll
        for (int n = 0; n < 4; ++n) {
            const int col = (nt0 + n) * 16 + (lane & 15);
            #pragma unroll
            for (int reg = 0; reg < 4; ++reg) {
                out[(size_t)(m0 + r0 + reg) * NV + col] = acc0[n][reg] + acc1[n][reg] + bias[n];
            }
        }
    }
}

// ---------------- Kernel C (fallback, fp32 vector) ----------------
__global__ __launch_bounds__(256) void k_dense(
    const float* __restrict__ y, const float* __restrict__ Wd,
    const float* __restrict__ bd, float* __restrict__ out)
{
    __shared__ float ys[64 * HD];
    const int r0 = blockIdx.x * 64;
    const int v0 = blockIdx.y * 128;
    const int tid = threadIdx.x;
    for (int idx = tid; idx < 64 * HD; idx += 256) ys[idx] = y[(size_t)r0 * HD + idx];
    __syncthreads();
    const int tx = tid & 31;
    const int ty = tid >> 5;
    const int v = v0 + tx * 4;
    float4 bd4 = *(const float4*)&bd[v];
    float acc[8][4] = {};
    const float* yrow = &ys[(ty * 8) * HD];
    #pragma unroll 4
    for (int e = 0; e < HD; ++e) {
        float4 wv = *(const float4*)&Wd[(size_t)e * NV + v];
        #pragma unroll
        for (int j = 0; j < 8; ++j) {
            float yv = yrow[j * HD + e];
            acc[j][0] = fmaf(yv, wv.x, acc[j][0]);
            acc[j][1] = fmaf(yv, wv.y, acc[j][1]);
            acc[j][2] = fmaf(yv, wv.z, acc[j][2]);
            acc[j][3] = fmaf(yv, wv.w, acc[j][3]);
        }
    }
    #pragma unroll
    for (int j = 0; j < 8; ++j) {
        int rr = r0 + ty * 8 + j;
        float4 o4;
        o4.x = acc[j][0] + bd4.x;
        o4.y = acc[j][1] + bd4.y;
        o4.z = acc[j][2] + bd4.z;
        o4.w = acc[j][3] + bd4.w;
        *(float4*)&out[(size_t)rr * NV + v] = o4;
    }
}

extern "C" void kernel_launch(void* const* d_in, const int* in_sizes, int n_in,
                              void* d_out, int out_size, void* d_ws, size_t ws_size,
                              hipStream_t stream)
{
    const int*   inputs = (const int*)  d_in[0];
    const float* emb    = (const float*)d_in[1];
    const float* W0     = (const float*)d_in[2];
    const float* U0     = (const float*)d_in[3];
    const float* b0     = (const float*)d_in[4];
    const float* W1     = (const float*)d_in[5];
    const float* U1     = (const float*)d_in[6];
    const float* b1     = (const float*)d_in[7];
    const float* Wd     = (const float*)d_in[8];
    const float* bd     = (const float*)d_in[9];
    float* out = (float*)d_out;

    // ws layout (MFMA path): Z0x 8MB | yy 2MB | Whi 8MB | Wlo 8MB | yhi 1MB | ylo 1MB
    const size_t Z0X_B = (size_t)8 * 1024 * 1024;
    const size_t YY_B  = (size_t)2 * 1024 * 1024;
    const size_t WSP_B = (size_t)8000 * 512 * 2;        // 8,192,000
    const size_t YSP_B = (size_t)1024 * 512 * 2;        // 1,048,576
    const size_t NEED  = Z0X_B + YY_B + 2 * WSP_B + 2 * YSP_B + 4096;

    char* ws = (char*)d_ws;

    if (ws_size >= NEED) {
        float*     Z0x = (float*)ws;
        float*     yy  = (float*)(ws + Z0X_B);
        _Float16*  Whi = (_Float16*)(ws + Z0X_B + YY_B);
        _Float16*  Wlo = (_Float16*)(ws + Z0X_B + YY_B + WSP_B);
        _Float16*  yhi = (_Float16*)(ws + Z0X_B + YY_B + 2 * WSP_B);
        _Float16*  ylo = (_Float16*)(ws + Z0X_B + YY_B + 2 * WSP_B + YSP_B);

        k_embed<<<512, 256, 0, stream>>>(inputs, emb, W0, b0, Z0x);
        k_lstm_w8<<<1004, 512, 0, stream>>>(Z0x, U0, W1, U1, b1, yy, Wd, Whi, Wlo);
        k_ysplit<<<256, 256, 0, stream>>>(yy, yhi, ylo);
        k_dense_mfma2<<<dim3(8, 125), 256, 0, stream>>>(yhi, ylo, Whi, Wlo, bd, out);
    } else {
        // small-ws fallback: Z0x in d_out tail, yy in ws, fp32 dense
        float* yy = (float*)ws;
        size_t out_bytes = (size_t)out_size * sizeof(float);
        float* Z0x = (float*)((char*)d_out + out_bytes - Z0X_B);

        k_embed<<<512, 256, 0, stream>>>(inputs, emb, W0, b0, Z0x);
        k_lstm_w8<<<1004, 512, 0, stream>>>(Z0x, U0, W1, U1, b1, yy,
                                            Wd, nullptr, nullptr);
        k_dense<<<dim3(64, 250), 256, 0, stream>>>(yy, Wd, bd, out);
    }
}